// Round 1
// baseline (52.032 us; speedup 1.0000x reference)
//
#include <hip/hip_runtime.h>

// Problem constants (from reference)
static constexpr int   B_TOTAL  = 4194304;
static constexpr unsigned POS_MASK = 0xD2u; // classes 1,4,6,7 are POSITIVE: bits 1,4,6,7
static constexpr int   BLOCKS   = 2048;
static constexpr int   THREADS  = 256;

// Weighted CE for one 8-class sample held in two float4s.
// All register, no runtime-indexed arrays (avoids scratch).
__device__ __forceinline__ float wce8(const float4 lo, const float4 hi, const int lbl) {
    const float x0 = lo.x, x1 = lo.y, x2 = lo.z, x3 = lo.w;
    const float x4 = hi.x, x5 = hi.y, x6 = hi.z, x7 = hi.w;

    // max + argmax (first occurrence wins ties via strict >)
    float m = x0; int am = 0;
    if (x1 > m) { m = x1; am = 1; }
    if (x2 > m) { m = x2; am = 2; }
    if (x3 > m) { m = x3; am = 3; }
    if (x4 > m) { m = x4; am = 4; }
    if (x5 > m) { m = x5; am = 5; }
    if (x6 > m) { m = x6; am = 6; }
    if (x7 > m) { m = x7; am = 7; }

    // log-sum-exp
    float s = __expf(x0 - m) + __expf(x1 - m) + __expf(x2 - m) + __expf(x3 - m)
            + __expf(x4 - m) + __expf(x5 - m) + __expf(x6 - m) + __expf(x7 - m);
    const float logZ = m + __logf(s);

    // x[lbl] via select chain (compile-time indices only)
    float xl = x0;
    xl = (lbl == 1) ? x1 : xl;
    xl = (lbl == 2) ? x2 : xl;
    xl = (lbl == 3) ? x3 : xl;
    xl = (lbl == 4) ? x4 : xl;
    xl = (lbl == 5) ? x5 : xl;
    xl = (lbl == 6) ? x6 : xl;
    xl = (lbl == 7) ? x7 : xl;

    const unsigned diff = ((POS_MASK >> lbl) ^ (POS_MASK >> am)) & 1u;
    const float w = 1.0f + 0.5f * (float)diff;
    return (logZ - xl) * w;
}

__device__ __forceinline__ float block_reduce(float acc) {
    // wave (64-lane) shuffle reduce
    #pragma unroll
    for (int off = 32; off > 0; off >>= 1)
        acc += __shfl_down(acc, off);
    __shared__ float smem[THREADS / 64];
    const int wave = threadIdx.x >> 6;
    if ((threadIdx.x & 63) == 0) smem[wave] = acc;
    __syncthreads();
    float t = 0.0f;
    if (threadIdx.x == 0) {
        #pragma unroll
        for (int w = 0; w < THREADS / 64; ++w) t += smem[w];
    }
    return t; // valid only on thread 0
}

__global__ __launch_bounds__(THREADS) void pcce_main(
    const float* __restrict__ a, const float* __restrict__ v,
    const int* __restrict__ y, float* __restrict__ partials, const int n)
{
    const float4* __restrict__ a4 = reinterpret_cast<const float4*>(a);
    const float4* __restrict__ v4 = reinterpret_cast<const float4*>(v);
    const int tid    = blockIdx.x * blockDim.x + threadIdx.x;
    const int stride = gridDim.x * blockDim.x;

    float acc = 0.0f;
    for (int i = tid; i < n; i += stride) {
        const int lbl = y[i];
        const float4 alo = a4[2 * i], ahi = a4[2 * i + 1];
        const float4 vlo = v4[2 * i], vhi = v4[2 * i + 1];
        acc += wce8(alo, ahi, lbl);
        acc += wce8(vlo, vhi, lbl);
    }

    const float t = block_reduce(acc);
    if (threadIdx.x == 0) partials[blockIdx.x] = t;
}

// Fallback path (no-ws): atomic accumulate directly into out (pre-zeroed).
__global__ __launch_bounds__(THREADS) void pcce_main_atomic(
    const float* __restrict__ a, const float* __restrict__ v,
    const int* __restrict__ y, float* __restrict__ out, const int n)
{
    const float4* __restrict__ a4 = reinterpret_cast<const float4*>(a);
    const float4* __restrict__ v4 = reinterpret_cast<const float4*>(v);
    const int tid    = blockIdx.x * blockDim.x + threadIdx.x;
    const int stride = gridDim.x * blockDim.x;

    float acc = 0.0f;
    for (int i = tid; i < n; i += stride) {
        const int lbl = y[i];
        const float4 alo = a4[2 * i], ahi = a4[2 * i + 1];
        const float4 vlo = v4[2 * i], vhi = v4[2 * i + 1];
        acc += wce8(alo, ahi, lbl);
        acc += wce8(vlo, vhi, lbl);
    }

    const float t = block_reduce(acc);
    if (threadIdx.x == 0) atomicAdd(out, t * (1.0f / (float)B_TOTAL));
}

__global__ __launch_bounds__(256) void pcce_reduce(
    const float* __restrict__ partials, const int nb, float* __restrict__ out)
{
    float acc = 0.0f;
    for (int i = threadIdx.x; i < nb; i += 256) acc += partials[i];
    #pragma unroll
    for (int off = 32; off > 0; off >>= 1)
        acc += __shfl_down(acc, off);
    __shared__ float smem[4];
    if ((threadIdx.x & 63) == 0) smem[threadIdx.x >> 6] = acc;
    __syncthreads();
    if (threadIdx.x == 0)
        out[0] = (smem[0] + smem[1] + smem[2] + smem[3]) * (1.0f / (float)B_TOTAL);
}

extern "C" void kernel_launch(void* const* d_in, const int* in_sizes, int n_in,
                              void* d_out, int out_size, void* d_ws, size_t ws_size,
                              hipStream_t stream) {
    const float* a = (const float*)d_in[0];
    const float* v = (const float*)d_in[1];
    const int*   y = (const int*)d_in[2];
    float* out = (float*)d_out;
    const int n = in_sizes[2]; // B

    if (ws_size >= (size_t)BLOCKS * sizeof(float)) {
        float* partials = (float*)d_ws;
        pcce_main<<<BLOCKS, THREADS, 0, stream>>>(a, v, y, partials, n);
        pcce_reduce<<<1, 256, 0, stream>>>(partials, BLOCKS, out);
    } else {
        // deterministic-enough fallback: zero out then atomic accumulate
        hipMemsetAsync(out, 0, sizeof(float), stream);
        pcce_main_atomic<<<BLOCKS, THREADS, 0, stream>>>(a, v, y, out, n);
    }
}